// Round 1
// baseline (115.080 us; speedup 1.0000x reference)
//
#include <hip/hip_runtime.h>

#define B_   8
#define C_   128
#define H_   128
#define W_   128
#define TILE 16
#define PAD  3
#define HALO (TILE + 2*PAD)      // 22
#define NPOS (HALO*HALO)         // 484
#define NC   4                   // channels interleaved per LDS tile (float4)
#define CPB  32                  // channels per block
#define NGRP (CPB/NC)            // 8 groups
#define NCHUNK (C_/CPB)          // 4

__device__ __forceinline__ int refl(int i, int n) {
    if (i < 0) i = -i;
    if (i >= n) i = 2*n - 2 - i;
    return i;
}

__global__ __launch_bounds__(256, 4) void ddconv_kernel(
    const float* __restrict__ x,      // [B,C,H,W]
    const float* __restrict__ angle,  // [B,H,W]
    const float* __restrict__ w1,     // [8,2]
    const float* __restrict__ b1,     // [8]
    const float* __restrict__ w2,     // [4,8]
    const float* __restrict__ b2,     // [4]
    const float* __restrict__ bk,     // [4,7,7]
    float* __restrict__ out)          // [B,C,H,W]
{
    __shared__ float  sK[4*49];
    __shared__ float4 buf[2][NPOS];   // 2 * 484 * 16 B = 15488 B

    const int tid = threadIdx.x;
    const int px  = tid & (TILE-1);
    const int py  = tid >> 4;
    const int bx  = blockIdx.x;               // 64 tiles (8x8)
    const int tx0 = (bx & 7) * TILE;
    const int ty0 = (bx >> 3) * TILE;
    const int b   = blockIdx.y;
    const int c0  = blockIdx.z * CPB;
    const int h   = ty0 + py;
    const int w   = tx0 + px;
    const size_t HW = (size_t)H_ * W_;

    if (tid < 196) sK[tid] = bk[tid];

    // ---- per-pixel gating weights (MLP 2->8->4 + softmax) ----
    float a = angle[((size_t)b*H_ + h)*W_ + w];
    float s = __sinf(2.f*a), c = __cosf(2.f*a);
    float hv[8];
#pragma unroll
    for (int j = 0; j < 8; ++j) {
        float v = fmaf(s, w1[2*j], fmaf(c, w1[2*j+1], b1[j]));
        hv[j] = v > 0.f ? v : 0.f;
    }
    float lg[4];
#pragma unroll
    for (int d = 0; d < 4; ++d) {
        float v = b2[d];
#pragma unroll
        for (int j = 0; j < 8; ++j) v = fmaf(hv[j], w2[d*8+j], v);
        lg[d] = v;
    }
    float m  = fmaxf(fmaxf(lg[0], lg[1]), fmaxf(lg[2], lg[3]));
    float e0 = __expf(lg[0]-m), e1 = __expf(lg[1]-m);
    float e2 = __expf(lg[2]-m), e3 = __expf(lg[3]-m);
    float inv = 1.f / (e0+e1+e2+e3);
    float wt0 = e0*inv, wt1 = e1*inv, wt2 = e2*inv, wt3 = e3*inv;

    __syncthreads();   // sK staged

    // ---- blend per-pixel 7x7 kernel, held in 49 VGPRs ----
    float kb[49];
#pragma unroll
    for (int t = 0; t < 49; ++t)
        kb[t] = wt0*sK[t] + wt1*sK[49+t] + wt2*sK[98+t] + wt3*sK[147+t];

    // ---- staging geometry (each thread loads up to 2 halo positions) ----
    const int p0 = tid;
    const int p1 = tid + 256;
    const bool has1 = (p1 < NPOS);
    const int gy0 = refl(ty0 + p0/HALO - PAD, H_);
    const int gx0 = refl(tx0 + p0%HALO - PAD, W_);
    const int gy1 = refl(ty0 + (has1 ? p1/HALO : 0) - PAD, H_);
    const int gx1 = refl(tx0 + (has1 ? p1%HALO : 0) - PAD, W_);
    const int off0 = gy0*W_ + gx0;
    const int off1 = gy1*W_ + gx1;

    // prologue: stage group 0 into buf[0]
    {
        const float* xb = x + ((size_t)(b*C_ + c0))*HW;
        float4 v0, v1;
        v0.x = xb[0*HW + off0]; v0.y = xb[1*HW + off0];
        v0.z = xb[2*HW + off0]; v0.w = xb[3*HW + off0];
        if (has1) {
            v1.x = xb[0*HW + off1]; v1.y = xb[1*HW + off1];
            v1.z = xb[2*HW + off1]; v1.w = xb[3*HW + off1];
        }
        buf[0][p0] = v0;
        if (has1) buf[0][p1] = v1;
    }

    for (int g = 0; g < NGRP; ++g) {
        __syncthreads();   // buf[g&1] ready; buf[(g+1)&1]'s readers (iter g-1) done

        // issue next group's global loads EARLY (latency hides under compute)
        float4 v0, v1;
        const bool doStage = (g + 1 < NGRP);
        if (doStage) {
            const float* xb = x + ((size_t)(b*C_ + c0 + (g+1)*NC))*HW;
            v0.x = xb[0*HW + off0]; v0.y = xb[1*HW + off0];
            v0.z = xb[2*HW + off0]; v0.w = xb[3*HW + off0];
            if (has1) {
                v1.x = xb[0*HW + off1]; v1.y = xb[1*HW + off1];
                v1.z = xb[2*HW + off1]; v1.w = xb[3*HW + off1];
            }
        }

        // ---- 7x7 conv on 4 interleaved channels from LDS ----
        const float4* tb = buf[g & 1];
        float ax = 0.f, ay = 0.f, az = 0.f, aw = 0.f;
#pragma unroll
        for (int i = 0; i < 7; ++i) {
#pragma unroll
            for (int j = 0; j < 7; ++j) {
                float4 v = tb[(py+i)*HALO + (px+j)];
                float k = kb[i*7+j];
                ax = fmaf(v.x, k, ax);
                ay = fmaf(v.y, k, ay);
                az = fmaf(v.z, k, az);
                aw = fmaf(v.w, k, aw);
            }
        }
        float* ob = out + ((size_t)(b*C_ + c0 + g*NC))*HW + (size_t)h*W_ + w;
        ob[0*HW] = ax; ob[1*HW] = ay; ob[2*HW] = az; ob[3*HW] = aw;

        // write-late: LDS store of next group's tile
        if (doStage) {
            buf[(g+1) & 1][p0] = v0;
            if (has1) buf[(g+1) & 1][p1] = v1;
        }
    }
}

extern "C" void kernel_launch(void* const* d_in, const int* in_sizes, int n_in,
                              void* d_out, int out_size, void* d_ws, size_t ws_size,
                              hipStream_t stream) {
    const float* x     = (const float*)d_in[0];
    const float* angle = (const float*)d_in[1];
    const float* w1    = (const float*)d_in[2];
    const float* b1    = (const float*)d_in[3];
    const float* w2    = (const float*)d_in[4];
    const float* b2    = (const float*)d_in[5];
    const float* bk    = (const float*)d_in[6];
    float* out = (float*)d_out;

    dim3 grid((H_/TILE)*(W_/TILE), B_, NCHUNK);   // 64 x 8 x 4 = 2048 blocks
    dim3 block(256);
    ddconv_kernel<<<grid, block, 0, stream>>>(x, angle, w1, b1, w2, b2, bk, out);
}

// Round 2
// 54.781 us; speedup vs baseline: 2.1007x; 2.1007x over previous
//
#include <hip/hip_runtime.h>

#define B_   8
#define C_   128
#define H_   128
#define W_   128
#define TX   32
#define TY   16
#define PAD  3
#define HX   (TX + 2*PAD)        // 38
#define HY   (TY + 2*PAD)        // 22
#define NPOS (HX*HY)             // 836
#define NC   4                   // channels interleaved per LDS float4
#define CPB  16                  // channels per block
#define NGRP (CPB/NC)            // 4 groups
#define NCHUNK (C_/CPB)          // 8

__device__ __forceinline__ int refl(int i, int n) {
    if (i < 0) i = -i;
    if (i >= n) i = 2*n - 2 - i;
    return i;
}

__global__ __launch_bounds__(256, 3) void ddconv_kernel(
    const float* __restrict__ x,      // [B,C,H,W]
    const float* __restrict__ angle,  // [B,H,W]
    const float* __restrict__ w1,     // [8,2]
    const float* __restrict__ b1,     // [8]
    const float* __restrict__ w2,     // [4,8]
    const float* __restrict__ b2,     // [4]
    const float* __restrict__ bk,     // [4,7,7]
    float* __restrict__ out)          // [B,C,H,W]
{
    __shared__ float  sK[4*49];
    __shared__ float4 buf[2][NPOS];   // 2 * 836 * 16 B = 26752 B

    const int tid = threadIdx.x;
    const int tx  = tid & 31;          // 0..31
    const int ty2 = tid >> 5;          // 0..7  -> rows 2*ty2, 2*ty2+1
    const int bx  = blockIdx.x;        // 32 tiles (4 in x, 8 in y)
    const int TX0 = (bx & 3) * TX;
    const int TY0 = (bx >> 2) * TY;
    const int b   = blockIdx.y;
    const int c0  = blockIdx.z * CPB;
    const int y0  = TY0 + 2*ty2;
    const int wv  = TX0 + tx;
    const size_t HW = (size_t)H_ * W_;

    if (tid < 196) sK[tid] = bk[tid];

    // ---- per-pixel gating weights for the 2 vertical pixels ----
    float wt[2][4];
#pragma unroll
    for (int p = 0; p < 2; ++p) {
        float a = angle[((size_t)b*H_ + (y0+p))*W_ + wv];
        float s = __sinf(2.f*a), c = __cosf(2.f*a);
        float hv[8];
#pragma unroll
        for (int j = 0; j < 8; ++j) {
            float v = fmaf(s, w1[2*j], fmaf(c, w1[2*j+1], b1[j]));
            hv[j] = v > 0.f ? v : 0.f;
        }
        float lg[4];
#pragma unroll
        for (int d = 0; d < 4; ++d) {
            float v = b2[d];
#pragma unroll
            for (int j = 0; j < 8; ++j) v = fmaf(hv[j], w2[d*8+j], v);
            lg[d] = v;
        }
        float m  = fmaxf(fmaxf(lg[0], lg[1]), fmaxf(lg[2], lg[3]));
        float e0 = __expf(lg[0]-m), e1 = __expf(lg[1]-m);
        float e2 = __expf(lg[2]-m), e3 = __expf(lg[3]-m);
        float inv = 1.f / (e0+e1+e2+e3);
        wt[p][0] = e0*inv; wt[p][1] = e1*inv; wt[p][2] = e2*inv; wt[p][3] = e3*inv;
    }

    // ---- staging geometry: 4 slots per thread cover 836 positions ----
    int off[4];
#pragma unroll
    for (int s = 0; s < 4; ++s) {
        int p = tid + s*256;
        if (p >= NPOS) p = NPOS - 1;   // harmless duplicate addr for masked slot
        int gy = refl(TY0 + p/HX - PAD, H_);
        int gx = refl(TX0 + p%HX - PAD, W_);
        off[s] = gy*W_ + gx;
    }
    const bool has3 = (tid + 768 < NPOS);

    // prologue: stage group 0 into buf[0]
    {
        const float* xb = x + ((size_t)(b*C_ + c0))*HW;
#pragma unroll
        for (int s = 0; s < 3; ++s) {
            float4 v;
            v.x = xb[0*HW + off[s]]; v.y = xb[1*HW + off[s]];
            v.z = xb[2*HW + off[s]]; v.w = xb[3*HW + off[s]];
            buf[0][tid + s*256] = v;
        }
        if (has3) {
            float4 v;
            v.x = xb[0*HW + off[3]]; v.y = xb[1*HW + off[3]];
            v.z = xb[2*HW + off[3]]; v.w = xb[3*HW + off[3]];
            buf[0][tid + 768] = v;
        }
    }

    __syncthreads();   // sK + buf[0] ready

    // ---- blend the two per-pixel 7x7 kernels into VGPRs ----
    float kb0[49], kb1[49];
#pragma unroll
    for (int t = 0; t < 49; ++t) {
        float s0 = sK[t], s1 = sK[49+t], s2 = sK[98+t], s3 = sK[147+t];
        kb0[t] = wt[0][0]*s0 + wt[0][1]*s1 + wt[0][2]*s2 + wt[0][3]*s3;
        kb1[t] = wt[1][0]*s0 + wt[1][1]*s1 + wt[1][2]*s2 + wt[1][3]*s3;
    }

    for (int g = 0; g < NGRP; ++g) {
        if (g > 0) __syncthreads();   // buf[g&1] ready; prior readers of buf[(g+1)&1] done

        // issue next group's global loads EARLY
        float4 v0, v1, v2, v3;
        const bool doStage = (g + 1 < NGRP);
        if (doStage) {
            const float* xb = x + ((size_t)(b*C_ + c0 + (g+1)*NC))*HW;
            v0.x = xb[0*HW + off[0]]; v0.y = xb[1*HW + off[0]];
            v0.z = xb[2*HW + off[0]]; v0.w = xb[3*HW + off[0]];
            v1.x = xb[0*HW + off[1]]; v1.y = xb[1*HW + off[1]];
            v1.z = xb[2*HW + off[1]]; v1.w = xb[3*HW + off[1]];
            v2.x = xb[0*HW + off[2]]; v2.y = xb[1*HW + off[2]];
            v2.z = xb[2*HW + off[2]]; v2.w = xb[3*HW + off[2]];
            if (has3) {
                v3.x = xb[0*HW + off[3]]; v3.y = xb[1*HW + off[3]];
                v3.z = xb[2*HW + off[3]]; v3.w = xb[3*HW + off[3]];
            }
        }

        // ---- 7x7 conv, 2 vertical pixels x 4 interleaved channels ----
        const float4* tb = buf[g & 1];
        float4 acc0 = {0.f,0.f,0.f,0.f}, acc1 = {0.f,0.f,0.f,0.f};
#pragma unroll
        for (int r = 0; r < 8; ++r) {
            float4 win[7];
            const int base = (2*ty2 + r)*HX + tx;
#pragma unroll
            for (int j = 0; j < 7; ++j) win[j] = tb[base + j];
            if (r < 7) {
#pragma unroll
                for (int j = 0; j < 7; ++j) {
                    float k = kb0[r*7 + j];
                    acc0.x = fmaf(win[j].x, k, acc0.x);
                    acc0.y = fmaf(win[j].y, k, acc0.y);
                    acc0.z = fmaf(win[j].z, k, acc0.z);
                    acc0.w = fmaf(win[j].w, k, acc0.w);
                }
            }
            if (r >= 1) {
#pragma unroll
                for (int j = 0; j < 7; ++j) {
                    float k = kb1[(r-1)*7 + j];
                    acc1.x = fmaf(win[j].x, k, acc1.x);
                    acc1.y = fmaf(win[j].y, k, acc1.y);
                    acc1.z = fmaf(win[j].z, k, acc1.z);
                    acc1.w = fmaf(win[j].w, k, acc1.w);
                }
            }
        }

        float* ob = out + ((size_t)(b*C_ + c0 + g*NC))*HW + (size_t)y0*W_ + wv;
        ob[0*HW]      = acc0.x; ob[1*HW]      = acc0.y;
        ob[2*HW]      = acc0.z; ob[3*HW]      = acc0.w;
        ob[0*HW + W_] = acc1.x; ob[1*HW + W_] = acc1.y;
        ob[2*HW + W_] = acc1.z; ob[3*HW + W_] = acc1.w;

        // write-late: LDS store of next group's tile
        if (doStage) {
            float4* nb = buf[(g+1) & 1];
            nb[tid]       = v0;
            nb[tid + 256] = v1;
            nb[tid + 512] = v2;
            if (has3) nb[tid + 768] = v3;
        }
    }
}

extern "C" void kernel_launch(void* const* d_in, const int* in_sizes, int n_in,
                              void* d_out, int out_size, void* d_ws, size_t ws_size,
                              hipStream_t stream) {
    const float* x     = (const float*)d_in[0];
    const float* angle = (const float*)d_in[1];
    const float* w1    = (const float*)d_in[2];
    const float* b1    = (const float*)d_in[3];
    const float* w2    = (const float*)d_in[4];
    const float* b2    = (const float*)d_in[5];
    const float* bk    = (const float*)d_in[6];
    float* out = (float*)d_out;

    dim3 grid((W_/TX)*(H_/TY), B_, NCHUNK);   // 32 x 8 x 8 = 2048 blocks
    dim3 block(256);
    ddconv_kernel<<<grid, block, 0, stream>>>(x, angle, w1, b1, w2, b2, bk, out);
}